// Round 5
// baseline (532.811 us; speedup 1.0000x reference)
//
#include <hip/hip_runtime.h>

// LittleBitITQSpecLinear: y = sum_b ((x*v2_b) @ sign(V_b)^T * (v1_b*u2_b)) @ sign(U_b)^T * u1_b + bias
// Folded: W1_b[s,k] = sign(V_b[s,k])*v2_b[k];  W2_b[o,s] = sign(U_b[o,s])*v1_b[s]*u2_b[s]*u1_b[o]
// => H = Xbf16 @ W1cat^T  (8192x2048, K=4096);  Y = H @ W2cat^T + bias (8192x4096, K=2048)
//
// R7: slice-aligned LDS regions -> m201-depth pipeline with full barrier
// safety. R6's fail: its vmcnt checkpoint retired loads only 2 phases old
// (~340cy cover < 500-900cy latency) -> stall at every checkpoint.
// Fix: LDS regions = read slices (As[buf][mh], Bs[buf][nh]); each region is
// read in exactly ONE phase (B0@ph1,A0@ph1,B1@ph2,A1@ph3), so staging can run
// a full K-tile ahead INTO the live buffer with every overwrite still
// barrier-ordered >=2 barriers after the region's last read (R5's proven
// safety class). Slot map (iter i, tiles e=2i,o=2i+1 consumed; f=2i+2,g=2i+3
// staged): ph1 o.A1, ph2 f.B0, ph3 f.A0, ph4 f.B1, ph5 f.A1, ph6 g.B0,
// ph7 g.A0, ph8 g.B1 (g.A1 at next iter's ph1). Ledger: VMW(6) at ph4
// retires o.{B0,A0,B1,A1} (youngest 3 phases old, oldest 7); VMW(6) at ph8
// retires f. Reader RAW: every region is VMW+BAR-published before its read.
// global_load_lds per-lane GLOBAL addressing realizes the slice->linear-LDS
// gather (LDS dest stays base+tid*16 as HW requires).

typedef __bf16 bf16x8 __attribute__((ext_vector_type(8)));
typedef float floatx4 __attribute__((ext_vector_type(4)));

__device__ __forceinline__ unsigned short f2bf_rne(float f) {
    union { float f; unsigned u; } v; v.f = f;
    unsigned r = v.u + 0x7FFFu + ((v.u >> 16) & 1u);
    return (unsigned short)(r >> 16);
}

__device__ __forceinline__ float sgnf(float w) {
    return (float)((w > 0.f) - (w < 0.f));
}

__device__ __forceinline__ void async_copy16(const void* g, void* l) {
    __builtin_amdgcn_global_load_lds(
        (const __attribute__((address_space(1))) void*)g,
        (__attribute__((address_space(3))) void*)l, 16, 0, 0);
}

#define FENCE() asm volatile("" ::: "memory")
#define BAR() do { FENCE(); __builtin_amdgcn_s_barrier(); FENCE(); } while (0)
#define VMW(N) asm volatile("s_waitcnt vmcnt(" #N ")" ::: "memory")
#define LGKM(N) asm volatile("s_waitcnt lgkmcnt(" #N ")" ::: "memory")

// ---------------- fused prep kernel (unchanged, proven) ----------------
// Blocks [0,32768): cast x -> bf16. [32768,40960): W1cat. [40960,49152): W2cat.

__global__ void prep_all_kernel(const float* __restrict__ x,
                                unsigned short* __restrict__ xb,
                                const float* __restrict__ V, const float* __restrict__ V_R,
                                const float* __restrict__ v2, const float* __restrict__ v2_R,
                                const float* __restrict__ U, const float* __restrict__ U_R,
                                const float* __restrict__ v1, const float* __restrict__ v1_R,
                                const float* __restrict__ u2, const float* __restrict__ u2_R,
                                const float* __restrict__ u1, const float* __restrict__ u1_R,
                                unsigned short* __restrict__ W1,
                                unsigned short* __restrict__ W2) {
    int bid = blockIdx.x;
    if (bid < 32768) {
        int i = bid * blockDim.x + threadIdx.x;
        float4 v = ((const float4*)x)[i];
        ushort4 o;
        o.x = f2bf_rne(v.x); o.y = f2bf_rne(v.y);
        o.z = f2bf_rne(v.z); o.w = f2bf_rne(v.w);
        ((ushort4*)xb)[i] = o;
    } else if (bid < 40960) {
        int i = (bid - 32768) * blockDim.x + threadIdx.x;
        int idx = i << 2;
        int scat = idx >> 12;
        int k = idx & 4095;
        const float* Vp; const float* sp;
        if (scat < 1024) { Vp = V + ((size_t)scat << 12); sp = v2; }
        else             { Vp = V_R + ((size_t)(scat - 1024) << 12); sp = v2_R; }
        float4 w = *(const float4*)(Vp + k);
        float4 s = *(const float4*)(sp + k);
        ushort4 o;
        o.x = f2bf_rne(sgnf(w.x) * s.x);
        o.y = f2bf_rne(sgnf(w.y) * s.y);
        o.z = f2bf_rne(sgnf(w.z) * s.z);
        o.w = f2bf_rne(sgnf(w.w) * s.w);
        ((ushort4*)W1)[i] = o;
    } else {
        int i = (bid - 40960) * blockDim.x + threadIdx.x;
        int idx = i << 2;
        int o = idx >> 11;
        int scat = idx & 2047;
        int branch = scat >> 10;
        int s = scat & 1023;
        const float* Up  = branch ? U_R  : U;
        const float* v1p = branch ? v1_R : v1;
        const float* u2p = branch ? u2_R : u2;
        float u1v = (branch ? u1_R : u1)[o];
        float4 w = *(const float4*)(Up + ((size_t)o << 10) + s);
        float4 a = *(const float4*)(v1p + s);
        float4 b = *(const float4*)(u2p + s);
        ushort4 out;
        out.x = f2bf_rne(sgnf(w.x) * a.x * b.x * u1v);
        out.y = f2bf_rne(sgnf(w.y) * a.y * b.y * u1v);
        out.z = f2bf_rne(sgnf(w.z) * a.z * b.z * u1v);
        out.w = f2bf_rne(sgnf(w.w) * a.w * b.w * u1v);
        ((ushort4*)W2)[i] = out;
    }
}

// ---------------- GEMM: C[M,N] = A[M,K] @ B[N,K]^T ----------------
// 256x256 tile, BK=64, 512 threads = 8 waves (2M x 4N), per-wave 128x64 out.
// LDS slice regions (8 KiB = 128 rows x 64 cols bf16 each):
//   As[buf][mh]: global A rows m0 + p*128 + mh*64 + t   (LDS row = p*64+t)
//   Bs[buf][nh]: global B rows n0 + q*64  + nh*32 + t   (LDS row = q*32+t)
// Reader mapping is IDENTICAL to the proven R0/R5 fragment math:
//   lda(mh): row warp_m*64 + mi*16 + fm  -> global m0+warp_m*128+mh*64+mi*16+fm
//   ldb(nh): row warp_n*32 + ni*16 + fm  -> global n0+warp_n*64+nh*32+ni*16+fm
// Fetch-side chunk-XOR swizzle key = (LDS row & 7) on both sides (0 conflicts,
// proven): staged key = srow&7, read key = fm&7; slice bases are 64-row
// aligned so keys match.

template <bool OUT_BF16, bool ADD_BIAS>
__global__ __launch_bounds__(512, 2)
void gemm256(const unsigned short* __restrict__ A,
             const unsigned short* __restrict__ B,
             void* __restrict__ Cv,
             const float* __restrict__ bias,
             int M, int N, int K, int ntn) {
    (void)M;
    __shared__ __align__(16) unsigned short As[2][2][128 * 64];
    __shared__ __align__(16) unsigned short Bs[2][2][128 * 64];

    const int tid = threadIdx.x;
    const int lane = tid & 63;
    const int wave = tid >> 6;
    const int warp_m = wave >> 2;   // 0..1
    const int warp_n = wave & 3;    // 0..3

    // XCD-aware swizzle (nwg % 8 == 0 for both GEMMs -> bijective)
    const int nwg = gridDim.x;
    const int hw = blockIdx.x;
    const int swz = (hw & 7) * (nwg >> 3) + (hw >> 3);
    const int tm = swz / ntn;
    const int tn = swz - tm * ntn;
    const int m0 = tm << 8;
    const int n0 = tn << 8;

    const int srow = tid >> 3;                          // 0..63
    const int scg8 = (((tid & 7) ^ (srow & 7)) << 3);   // swizzled chunk * 8
    const int ldst = tid << 3;                          // 0..4095 elems
    const size_t Ks = (size_t)K;

    // stage slice mh of tile kt into As[buf][mh]: instr j covers LDS rows
    // [j*64,(j+1)*64) = global rows m0 + j*128 + mh*64 + srow.
    auto stA = [&](int buf, int mh, int kt) {
        const unsigned short* g = A + (size_t)(m0 + (mh << 6) + srow) * Ks + (kt << 6) + scg8;
        async_copy16(g,             &As[buf][mh][ldst]);
        async_copy16(g + (Ks << 7), &As[buf][mh][4096 + ldst]);
    };
    // stage slice nh into Bs[buf][nh]: LDS row r2=q*32+t, q=(j*2)+(srow>>5),
    // t=srow&31 -> global row n0 + q*64 + nh*32 + t.
    auto stB = [&](int buf, int nh, int kt) {
        const unsigned short* g = B + (size_t)(n0 + ((srow >> 5) << 6) + (nh << 5) + (srow & 31)) * Ks
                                    + (kt << 6) + scg8;
        async_copy16(g,             &Bs[buf][nh][ldst]);
        async_copy16(g + (Ks << 7), &Bs[buf][nh][4096 + ldst]);
    };

    // fragment reads (read-side swizzle matches fetch-side)
    const int fm = lane & 15;
    const int cgl = lane >> 4;                // 0..3
    const int key = fm & 7;
    const int ok0 = ((cgl ^ key) << 3);       // elem offset, k-slice 0
    const int ok1 = (((4 | cgl) ^ key) << 3); // elem offset, k-slice 1

    auto lda = [&](bf16x8 (&dst)[4][2], int buf, int mh) {
        const unsigned short* base = &As[buf][mh][0];
#pragma unroll
        for (int mi = 0; mi < 4; ++mi) {
            const unsigned short* p = base + (((warp_m << 6) + (mi << 4) + fm) << 6);
            dst[mi][0] = *(const bf16x8*)(p + ok0);
            dst[mi][1] = *(const bf16x8*)(p + ok1);
        }
    };
    auto ldb = [&](bf16x8 (&dst)[2][2], int buf, int nh) {
        const unsigned short* base = &Bs[buf][nh][0];
#pragma unroll
        for (int ni = 0; ni < 2; ++ni) {
            const unsigned short* p = base + (((warp_n << 5) + (ni << 4) + fm) << 6);
            dst[ni][0] = *(const bf16x8*)(p + ok0);
            dst[ni][1] = *(const bf16x8*)(p + ok1);
        }
    };

    floatx4 acc[8][4];
#pragma unroll
    for (int i = 0; i < 8; ++i)
#pragma unroll
        for (int j = 0; j < 4; ++j)
#pragma unroll
            for (int r = 0; r < 4; ++r) acc[i][j][r] = 0.f;

    bf16x8 a0[4][2], a1[4][2], b0[2][2], b1[2][2];

#define MMAQ(aS, bS, MH, NH) do { \
    __builtin_amdgcn_s_setprio(1); \
    _Pragma("unroll") \
    for (int mi_ = 0; mi_ < 4; ++mi_) { \
      _Pragma("unroll") \
      for (int ni_ = 0; ni_ < 2; ++ni_) { \
        acc[(MH)*4 + mi_][(NH)*2 + ni_] = __builtin_amdgcn_mfma_f32_16x16x32_bf16( \
            aS[mi_][0], bS[ni_][0], acc[(MH)*4 + mi_][(NH)*2 + ni_], 0, 0, 0); \
        acc[(MH)*4 + mi_][(NH)*2 + ni_] = __builtin_amdgcn_mfma_f32_16x16x32_bf16( \
            aS[mi_][1], bS[ni_][1], acc[(MH)*4 + mi_][(NH)*2 + ni_], 0, 0, 0); \
      } } \
    __builtin_amdgcn_s_setprio(0); \
  } while (0)

    // ---- prologue: t0 all 4 slices + t1.{B0,A0,B1} = 14 loads;
    // VMW(6) retires t0's 8 -> resident; queue = t1.{B0,A0,B1} (invariant).
    stB(0, 0, 0); stA(0, 0, 0); stB(0, 1, 0); stA(0, 1, 0);
    stB(1, 0, 1); stA(1, 0, 1); stB(1, 1, 1);
    VMW(6);
    BAR();

    const int NT = K >> 6;
    for (int i = 0; i < (NT >> 1) - 1; ++i) {
        const int ok = 2 * i + 1, fk = 2 * i + 2, gk = 2 * i + 3;
        // ph1: Q00(e); stage o.A1 (buf1.A1 last read prev ph7; RAW: retired @C1)
        lda(a0, 0, 0); ldb(b0, 0, 0);
        stA(1, 1, ok);
        LGKM(8);
        BAR(); LGKM(0);
        MMAQ(a0, b0, 0, 0);
        BAR();
        // ph2: Q01(e); stage f.B0 (buf0.B0 read ph1 only -> dead)
        ldb(b1, 0, 1);
        stB(0, 0, fk);
        BAR(); LGKM(0);
        MMAQ(a0, b1, 0, 1);
        BAR();
        // ph3: Q11(e); stage f.A0 (buf0.A0 read ph1 only -> dead)
        lda(a1, 0, 1);
        stA(0, 0, fk);
        BAR(); LGKM(0);
        MMAQ(a1, b1, 1, 1);
        BAR();
        // ph4: Q10(e); stage f.B1 (buf0.B1 read ph2 -> dead); C1: VMW(6)
        // retires o.{B0,A0,B1,A1} (queue was 6+8=14) -> tile o resident.
        stB(0, 1, fk);
        MMAQ(a1, b0, 1, 0);
        VMW(6);
        BAR();
        // ph5: Q00(o); stage f.A1 (buf0.A1 read ph3 -> dead)
        lda(a0, 1, 0); ldb(b0, 1, 0);
        stA(0, 1, fk);
        LGKM(8);
        BAR(); LGKM(0);
        MMAQ(a0, b0, 0, 0);
        BAR();
        // ph6: Q01(o); stage g.B0 (buf1.B0 read ph5 -> dead)
        ldb(b1, 1, 1);
        stB(1, 0, gk);
        BAR(); LGKM(0);
        MMAQ(a0, b1, 0, 1);
        BAR();
        // ph7: Q11(o); stage g.A0 (buf1.A0 read ph5 -> dead)
        lda(a1, 1, 1);
        stA(1, 0, gk);
        BAR(); LGKM(0);
        MMAQ(a1, b1, 1, 1);
        BAR();
        // ph8: Q10(o); stage g.B1 (buf1.B1 read ph6 -> dead); C2: VMW(6)
        // retires f.{B0,A0,B1,A1} -> tile f resident for next ph1.
        stB(1, 1, gk);
        MMAQ(a1, b0, 1, 0);
        VMW(6);
        BAR();
    }
    // ---- epilogue: tiles E=NT-2 (buf0), O=NT-1 (buf1); queue = O.{B0,A0,B1}.
    {
        lda(a0, 0, 0); ldb(b0, 0, 0);
        stA(1, 1, NT - 1);                 // O.A1
        LGKM(8);
        BAR(); LGKM(0);
        MMAQ(a0, b0, 0, 0);
        BAR();
        ldb(b1, 0, 1);
        BAR(); LGKM(0);
        MMAQ(a0, b1, 0, 1);
        BAR();
        lda(a1, 0, 1);
        BAR(); LGKM(0);
        MMAQ(a1, b1, 1, 1);
        BAR();
        MMAQ(a1, b0, 1, 0);
        VMW(0);                            // retire O (oldest 5+, youngest 3 ph)
        BAR();
        // final tile O fully resident; no further LDS writes.
        lda(a0, 1, 0); ldb(b0, 1, 0);
        ldb(b1, 1, 1); lda(a1, 1, 1);
        MMAQ(a0, b0, 0, 0);
        MMAQ(a0, b1, 0, 1);
        MMAQ(a1, b1, 1, 1);
        MMAQ(a1, b0, 1, 0);
    }
#undef MMAQ

    // epilogue C-write: C/D layout col=lane&15, row=(lane>>4)*4+reg [m89]
    const int rq = (lane >> 4) << 2;
    const int col = lane & 15;
#pragma unroll
    for (int mi = 0; mi < 8; ++mi) {
#pragma unroll
        for (int r = 0; r < 4; ++r) {
            const int gm = m0 + (warp_m << 7) + (mi << 4) + rq + r;
            const size_t base = (size_t)gm * (size_t)N;
#pragma unroll
            for (int ni = 0; ni < 4; ++ni) {
                const int gn = n0 + (warp_n << 6) + (ni << 4) + col;
                float v = acc[mi][ni][r];
                if (ADD_BIAS) v += bias[gn];
                if (OUT_BF16)
                    ((unsigned short*)Cv)[base + gn] = f2bf_rne(v);
                else
                    ((float*)Cv)[base + gn] = v;
            }
        }
    }
}

// ---------------- launch ----------------

extern "C" void kernel_launch(void* const* d_in, const int* in_sizes, int n_in,
                              void* d_out, int out_size, void* d_ws, size_t ws_size,
                              hipStream_t stream) {
    const float* x    = (const float*)d_in[0];
    const float* V    = (const float*)d_in[1];
    const float* U    = (const float*)d_in[2];
    const float* v2   = (const float*)d_in[3];
    const float* v1   = (const float*)d_in[4];
    const float* u2   = (const float*)d_in[5];
    const float* u1   = (const float*)d_in[6];
    const float* V_R  = (const float*)d_in[7];
    const float* U_R  = (const float*)d_in[8];
    const float* v2_R = (const float*)d_in[9];
    const float* v1_R = (const float*)d_in[10];
    const float* u2_R = (const float*)d_in[11];
    const float* u1_R = (const float*)d_in[12];
    const float* bias = (const float*)d_in[13];
    float* out = (float*)d_out;

    char* ws = (char*)d_ws;
    unsigned short* Xb = (unsigned short*)ws;                                   // 64 MiB
    unsigned short* W1 = (unsigned short*)(ws + (size_t)67108864);              // 16 MiB
    unsigned short* W2 = (unsigned short*)(ws + (size_t)67108864 + 16777216);   // 16 MiB
    unsigned short* H  = (unsigned short*)(ws + (size_t)67108864 + 33554432);   // 32 MiB

    // fused prep: 32768 cast blocks + 8192 W1 blocks + 8192 W2 blocks
    prep_all_kernel<<<49152, 256, 0, stream>>>(x, Xb, V, V_R, v2, v2_R,
                                               U, U_R, v1, v1_R, u2, u2_R, u1, u1_R,
                                               W1, W2);

    // GEMM1: H[8192,2048] = Xb @ W1^T, K=4096  -> 32x8 = 256 tiles (1/CU)
    gemm256<true, false><<<dim3(256), 512, 0, stream>>>(Xb, W1, (void*)H, nullptr,
                                                        8192, 2048, 4096, 8);
    // GEMM2: Y[8192,4096] = H @ W2^T + bias, K=2048 -> 32x16 = 512 tiles (2/CU)
    gemm256<false, true><<<dim3(512), 512, 0, stream>>>(H, W2, (void*)out, bias,
                                                        8192, 4096, 2048, 16);
}